// Round 1
// baseline (215.361 us; speedup 1.0000x reference)
//
#include <hip/hip_runtime.h>
#include <math.h>

// Problem constants (fixed by the reference).
#define BB    1024
#define SS    277
#define RR    76
#define ZZ    56
#define NLHS  24
#define NROWS (BB*SS)                      // 283648
#define ROWS_PER_BLOCK 256
#define NBCE (NROWS/ROWS_PER_BLOCK)        // 1108 (exact)
#define NMOM ZZ                            // 56 (placed FIRST in the grid)
#define NBLK (NBCE + NMOM)                 // 1164
#define F4ROW 19                           // 76 floats = 19 float4 per row
#define F4BLK (ROWS_PER_BLOCK*F4ROW)       // 4864 float4 = 77824 B LDS tile
#define BLK_ELEMS (ROWS_PER_BLOCK*RR)      // 19456
#define TOTAL_ELEMS 21558272.0             // B*S*R

static_assert(NROWS % ROWS_PER_BLOCK == 0, "rows divide blocks");

#define LN2F  0.69314718056f
#define NLN2F (-144.26950409f)   /* -100 / ln2 */

// Direct global->LDS copy, 16 B per lane. LDS dest is wave-uniform base +
// lane*16 in hardware; our linear layout (consecutive lanes -> consecutive
// float4 slots) matches that exactly, so no swizzle hazard (guide §5 caveat).
__device__ __forceinline__ void gload_lds16(const float4* g, float4* l) {
    auto gp = reinterpret_cast<const __attribute__((address_space(1))) unsigned int*>(
        reinterpret_cast<uintptr_t>(g));
    auto lp = reinterpret_cast<__attribute__((address_space(3))) unsigned int*>(
        reinterpret_cast<uintptr_t>(l));
    __builtin_amdgcn_global_load_lds(gp, lp, 16, 0, 0);
}

// blocks [0, NMOM): moment kernel, one column j per block (runs under bce).
// blocks [NMOM, NBLK): masked-softmax BCE, R3-proven math (absmax 0).
//   NEW STRUCTURE (R5): all global traffic coalesced. Model tile staged
//   HBM->LDS via global_load_lds (no VGPR roundtrip); each thread re-reads
//   its row from LDS per pass (3 x 19 ds_read_b128). Row stride = 76 words
//   == 12 mod 32 -> the 64 lanes' b128 bases cover the 8 aligned 4-bank
//   groups 8x each: conflict-free, no padding needed. This removes the
//   304B-strided (address-diverged) global loads that made R4 latency-bound
//   at 13% HBM / 14% VALU.
__global__ __launch_bounds__(256, 2) void fused_kernel(
    const float* __restrict__ model,
    const float* __restrict__ target,
    const float* __restrict__ masks,
    const int*   __restrict__ ind_to_lhs,
    const float* __restrict__ mu,
    double* __restrict__ partials)
{
    __shared__ float4        sx[F4BLK];        // 77824 B staged model tile
    __shared__ unsigned int  smb[NLHS*4];      // 96-bit mask per lhs, padded
    __shared__ int           sm_lhs[RR];
    __shared__ unsigned char sm_idx[ROWS_PER_BLOCK];
    __shared__ float         sm_red[4];
    __shared__ float         sdot[4][64];      // mom path
    __shared__ float         ssum[4];

    const int tid = threadIdx.x;

    if (blockIdx.x < NMOM) {
        // ---------------- mom path: var[:,j] for j = blockIdx ----------------
        const int j    = blockIdx.x;
        const int w    = tid >> 6;
        const int lane = tid & 63;
        const int i    = (lane < ZZ) ? lane : 0;
        float dot = 0.f, s1 = 0.f;
        const int b0 = 256*w;
        #pragma unroll 4
        for (int b = b0; b < b0 + 256; ++b) {
            const float c = mu[b*ZZ + j];     // wave-uniform broadcast
            const float a = mu[b*ZZ + i];     // coalesced across lanes
            dot = fmaf(a, c, dot);
            s1 += c;
        }
        sdot[w][lane] = dot;
        if (lane == 0) ssum[w] = s1;
        __syncthreads();
        if (w == 0) {
            float term = 0.f;
            if (lane < ZZ) {
                const float var = (sdot[0][lane]+sdot[1][lane]+sdot[2][lane]+sdot[3][lane]) * (1.f/BB);
                const float ve  = var - ((lane == j) ? 1.f : 0.f);
                term = tanhf(ve) * ve * (1.f/(ZZ*ZZ));
                if (lane == j) {
                    const float am = (ssum[0]+ssum[1]+ssum[2]+ssum[3]) * (1.f/BB);
                    term = fmaf(am*am, 1.f/ZZ, term);
                }
            }
            #pragma unroll
            for (int off = 32; off; off >>= 1) term += __shfl_xor(term, off, 64);
            if (lane == 0) partials[blockIdx.x] = (double)term;
        }
        return;
    }

    // ---------------- bce path ----------------
    const int bce_blk = blockIdx.x - NMOM;
    const size_t blk_base = (size_t)bce_blk * BLK_ELEMS;

    if (tid < NLHS*4) smb[tid] = 0u;
    sm_idx[tid] = 0;
    __syncthreads();   // nothing in flight yet -> cheap barrier

    // Issue the 19 coalesced target loads FIRST (consumed pre-barrier), then
    // the 19 global->LDS model stages (consumed post-barrier). vmcnt retires
    // in issue order, so the scan's register consumption never waits on the
    // staging loads; both streams share one latency/BW window.
    float4 t[F4ROW];
    {
        const float4* t4 = (const float4*)(target + blk_base);
        #pragma unroll
        for (int k = 0; k < F4ROW; ++k) t[k] = t4[tid + 256*k];
    }
    {
        const float4* g4 = (const float4*)(model + blk_base);
        #pragma unroll
        for (int k = 0; k < F4ROW; ++k)
            gload_lds16(g4 + tid + 256*k, &sx[tid + 256*k]);
    }

    // Pack masks into bitmasks (parallel, LDS atomicOr). L2-resident reads.
    for (int e = tid; e < NLHS*RR; e += 256) {
        const int lhs = e / RR;
        const int r   = e - lhs*RR;
        if (masks[e] > 0.5f)
            atomicOr(&smb[lhs*4 + (r >> 5)], 1u << (r & 31));
    }
    if (tid < RR) sm_lhs[tid] = ind_to_lhs[tid];

    // Coalesced one-hot scan. A float4 never straddles rows (76 = 19 f4).
    // One-hot => exactly one writer per row; WRITE AT EACH HIT.
    #pragma unroll
    for (int k = 0; k < F4ROW; ++k) {
        const int v4 = tid + 256*k;
        const float4 tv = t[k];
        int he = -1;
        const int e = v4*4;
        if (tv.x > 0.5f) he = e;
        if (tv.y > 0.5f) he = e+1;
        if (tv.z > 0.5f) he = e+2;
        if (tv.w > 0.5f) he = e+3;
        if (he >= 0) {
            const int row = he / RR;
            sm_idx[row] = (unsigned char)(he - row*RR);
        }
    }
    __syncthreads();   // compiler drains vmcnt(0): staged model tile resident

    // --- per-row compute from LDS (bit-identical op sequence to R3/R4) ---
    const int true_r = (int)sm_idx[tid];
    const int lhs    = sm_lhs[true_r];
    const unsigned int mw0 = smb[lhs*4 + 0];
    const unsigned int mw1 = smb[lhs*4 + 1];
    const unsigned int mw2 = smb[lhs*4 + 2];

    const float4* xr = &sx[tid*F4ROW];   // byte addr tid*304, 16B-aligned

    // Pass A: masked row max.
    float mx = -1e30f;
    #pragma unroll
    for (int k = 0; k < F4ROW; ++k) {
        const float4 v = xr[k];
        #pragma unroll
        for (int c = 0; c < 4; ++c) {
            const int r = k*4 + c;
            const unsigned int mw = (r < 32) ? mw0 : ((r < 64) ? mw1 : mw2);
            const bool un = (mw >> (r & 31)) & 1u;
            const float xm = un ? (&v.x)[c] : -1e30f;
            mx = fmaxf(mx, xm);
        }
    }

    // Pass B: e_r = exp(x_r - mx) (masked -> 0), sum.
    float s = 0.f;
    #pragma unroll
    for (int k = 0; k < F4ROW; ++k) {
        const float4 v = xr[k];
        #pragma unroll
        for (int c = 0; c < 4; ++c) {
            const int r = k*4 + c;
            const unsigned int mw = (r < 32) ? mw0 : ((r < 64) ? mw1 : mw2);
            const bool un = (mw >> (r & 31)) & 1u;
            const float xm = un ? (&v.x)[c] : -1e30f;
            s += __expf(xm - mx);
        }
    }

    // Pass C: clamped log(1-p) over ALL r (log2-domain), plus p at target.
    // e recomputed with identical ops -> identical bits to pass B's e.
    const float inv = 1.f / s;
    float sum_l2 = 0.f;
    float p_true = 0.f;
    #pragma unroll
    for (int k = 0; k < F4ROW; ++k) {
        const float4 v = xr[k];
        #pragma unroll
        for (int c = 0; c < 4; ++c) {
            const int r = k*4 + c;
            const unsigned int mw = (r < 32) ? mw0 : ((r < 64) ? mw1 : mw2);
            const bool un = (mw >> (r & 31)) & 1u;
            const float xm = un ? (&v.x)[c] : -1e30f;
            const float ev = __expf(xm - mx);
            const float p  = ev * inv;
            const float l2 = __log2f(1.f - p);
            sum_l2 += fmaxf(l2, NLN2F);
            if (r == true_r) p_true = p;
        }
    }
    float row_sum = LN2F * sum_l2;
    // Swap the true_r element's non-target term for the target term.
    const float l1c_t = fmaxf(LN2F * __log2f(1.f - p_true), -100.f);
    const float lp_t  = fmaxf(__logf(p_true), -100.f);   // p_true==0 (masked) -> -100
    row_sum += lp_t - l1c_t;

    // Block reduce -> one double partial per block (no atomics).
    #pragma unroll
    for (int off = 32; off; off >>= 1) row_sum += __shfl_xor(row_sum, off, 64);
    if ((tid & 63) == 0) sm_red[tid >> 6] = row_sum;
    __syncthreads();
    if (tid == 0)
        partials[blockIdx.x] = (double)((sm_red[0] + sm_red[1]) + (sm_red[2] + sm_red[3]));
}

// Sum NBCE bce partials + NMOM mom partials with the right scales.
__global__ __launch_bounds__(256) void final_kernel(
    const double* __restrict__ partials, float* __restrict__ out)
{
    __shared__ double sred[4];
    const int tid = threadIdx.x;
    double s = 0.0;
    for (int k = NMOM + tid; k < NBLK; k += 256) s += partials[k];
    double m = (tid < NMOM) ? partials[tid] : 0.0;
    double val = s * (-(double)SS / TOTAL_ELEMS) + m;
    #pragma unroll
    for (int off = 32; off; off >>= 1) val += __shfl_xor(val, off, 64);
    if ((tid & 63) == 0) sred[tid >> 6] = val;
    __syncthreads();
    if (tid == 0) out[0] = (float)((sred[0] + sred[1]) + (sred[2] + sred[3]));
}

extern "C" void kernel_launch(void* const* d_in, const int* in_sizes, int n_in,
                              void* d_out, int out_size, void* d_ws, size_t ws_size,
                              hipStream_t stream) {
    const float* model  = (const float*)d_in[0];   // [B,S,R]
    const float* mu     = (const float*)d_in[1];   // [B,Z]
    // d_in[2] = log_var — unused by the reference output
    const float* target = (const float*)d_in[3];   // [B,S,R] one-hot
    const float* masks  = (const float*)d_in[4];   // [NLHS,R]
    const int*   ind    = (const int*)  d_in[5];   // [R]
    float* out  = (float*)d_out;
    double* acc = (double*)d_ws;   // [0..NMOM) mom partials, [NMOM..NBLK) bce partials

    fused_kernel<<<NBLK, ROWS_PER_BLOCK, 0, stream>>>(model, target, masks, ind, mu, acc);
    final_kernel<<<1, 256, 0, stream>>>(acc, out);
}